// Round 7
// baseline (633.543 us; speedup 1.0000x reference)
//
#include <hip/hip_runtime.h>

typedef unsigned short u16;
typedef unsigned int u32;
typedef __bf16 bf16x8 __attribute__((ext_vector_type(8)));
typedef float f32x16 __attribute__((ext_vector_type(16)));
typedef u16 u16x8 __attribute__((ext_vector_type(8)));

#define T_TOK 8192
#define HDIM 1024
#define IDIM 2816
#define NEXP 8
#define NPAIR (T_TOK * 2)
#define MAXRB 71
#define PADROWS (MAXRB * 256)         // 18176
#define PARTSZ ((size_t)PADROWS * HDIM)  // u16 elements per splitK slot

// workspace layout (bytes)
// meta @0 (1K) | pairs @1024 | inv @73728 |
#define XB_OFF   (147456u)
#define W13T_OFF (XB_OFF + 16777216u)            // w13^T bf16 [E][5632][1024]; part (2x bf16) aliases after gemm1
#define W2T_OFF  (W13T_OFF + 92274688u)          // w2^T bf16 [E][1024][2816]
#define H_OFF    (W2T_OFF + 46137344u)           // h bf16 [18176][2816]
#define WS_NEED  ((size_t)H_OFF + 102367232u)

__device__ __forceinline__ u16 f2bf(float f) {
  u32 u = __builtin_bit_cast(u32, f);
  u32 r = u + 0x7fffu + ((u >> 16) & 1u);
  return (u16)(r >> 16);
}
__device__ __forceinline__ float bf2f(u16 v) {
  u32 u = ((u32)v) << 16;
  return __builtin_bit_cast(float, u);
}

#define GLD16(g, l) __builtin_amdgcn_global_load_lds( \
    (const __attribute__((address_space(1))) void*)(g), \
    (__attribute__((address_space(3))) void*)(l), 16, 0, 0)

#define WAITVM(N) asm volatile("s_waitcnt vmcnt(" #N ")" ::: "memory")

__device__ __forceinline__ void pbar() {
  __builtin_amdgcn_sched_barrier(0);
  asm volatile("" ::: "memory");
  __builtin_amdgcn_s_barrier();
  asm volatile("" ::: "memory");
  __builtin_amdgcn_sched_barrier(0);
}

// ---------------- routing ----------------
__global__ void fillinit_k(int* __restrict__ pairs, int* __restrict__ meta) {
  if (blockIdx.x == 0 && threadIdx.x < 16) meta[threadIdx.x] = 0;
  pairs[blockIdx.x * 256 + threadIdx.x] = -1;
}

__global__ void count_k(const int* __restrict__ routing, int* __restrict__ meta) {
  int i = blockIdx.x * 256 + threadIdx.x;
  if (i < NPAIR) atomicAdd(&meta[routing[i]], 1);
}

// meta: [0..7] counts, [8..15] cursors, [16..23] startRow, [24] totalRB, [32..102] rbExpert
__global__ void scan_k(int* __restrict__ meta) {
  if (threadIdx.x == 0) {
    int rb = 0;
    for (int e = 0; e < NEXP; ++e) {
      meta[16 + e] = rb * 256;
      int nrb = (meta[e] + 255) >> 8;
      for (int i = 0; i < nrb; ++i) meta[32 + rb + i] = e;
      rb += nrb;
    }
    meta[24] = rb;
  }
}

__global__ void scatter_k(const int* __restrict__ routing, int* __restrict__ meta,
                          int* __restrict__ pairs, int* __restrict__ inv) {
  int i = blockIdx.x * 256 + threadIdx.x;
  if (i < NPAIR) {
    int e = routing[i];
    int pos = atomicAdd(&meta[8 + e], 1);
    int row = meta[16 + e] + pos;
    pairs[row] = i;
    inv[i] = row;
  }
}

// ---------------- converts ----------------
__global__ void conv_x(const float* __restrict__ in, u16* __restrict__ out) {
  int i = blockIdx.x * 256 + threadIdx.x;
  float4 a = ((const float4*)in)[2 * i];
  float4 b = ((const float4*)in)[2 * i + 1];
  u16x8 o = { f2bf(a.x), f2bf(a.y), f2bf(a.z), f2bf(a.w),
              f2bf(b.x), f2bf(b.y), f2bf(b.z), f2bf(b.w) };
  ((u16x8*)out)[i] = o;
}

// out[c][r] = bf16(in[r][c]); 64x64 tiles; XOR-swizzled LDS
#define TSW(r, c) (((((c) >> 2) ^ ((((r) >> 4) & 3) << 2)) << 2) | ((c) & 3))
__global__ void transpose_cvt(const float* __restrict__ in, u16* __restrict__ out,
                              int R, int C) {
  __shared__ float tile[64][68];
  size_t base = (size_t)blockIdx.z * (size_t)R * (size_t)C;
  in += base; out += base;
  int t = threadIdx.x;
  int r0 = blockIdx.y * 64, c0 = blockIdx.x * 64;
  int lr = t >> 4, cb = t & 15;
#pragma unroll
  for (int p = 0; p < 4; ++p) {
    int row = p * 16 + lr;
    float4 v = *(const float4*)&in[(size_t)(r0 + row) * C + c0 + cb * 4];
    int pc = ((cb ^ ((p & 3) << 2)) << 2);
    tile[row][pc] = v.x; tile[row][pc + 1] = v.y;
    tile[row][pc + 2] = v.z; tile[row][pc + 3] = v.w;
  }
  __syncthreads();
  int oc = t >> 2, g0 = (t & 3) * 2;
#pragma unroll
  for (int gg = 0; gg < 2; ++gg) {
    int g = g0 + gg;
    u16x8 o = { f2bf(tile[g * 8 + 0][TSW(g * 8 + 0, oc)]), f2bf(tile[g * 8 + 1][TSW(g * 8 + 1, oc)]),
                f2bf(tile[g * 8 + 2][TSW(g * 8 + 2, oc)]), f2bf(tile[g * 8 + 3][TSW(g * 8 + 3, oc)]),
                f2bf(tile[g * 8 + 4][TSW(g * 8 + 4, oc)]), f2bf(tile[g * 8 + 5][TSW(g * 8 + 5, oc)]),
                f2bf(tile[g * 8 + 6][TSW(g * 8 + 6, oc)]), f2bf(tile[g * 8 + 7][TSW(g * 8 + 7, oc)]) };
    *(u16x8*)&out[(size_t)(c0 + oc) * R + r0 + g * 8] = o;
  }
}

// ======================= GEMM1: 256x256, 32x32x16 MFMA, 4-phase/K-tile =======================
// LDS swizzle: f(row) = (row&7) ^ (((row>>3)&3)<<1) — folds row bits 3-4 so lanes
// sharing lane&7 (rows {r,r+8,r+16,r+24} x hi) hit 8 distinct 16B slots.
__global__ __launch_bounds__(512, 2) void gemm1_k(
    const u16* __restrict__ Xb, const u16* __restrict__ W13T,
    const int* __restrict__ pairs, const int* __restrict__ meta,
    const float* __restrict__ rwf, u16* __restrict__ Hb) {
  int lin = blockIdx.x + 22 * blockIdx.y;
  int xcd = lin & 7, slot = lin >> 3;
  int flat = (xcd < 2) ? xcd * 196 + slot : 392 + (xcd - 2) * 195 + slot;
  int bx = flat / 71, rb = flat % 71;
  if (rb >= meta[24]) return;
  const int e = meta[32 + rb];
  const int bn0 = bx * 128;
  const int tid = threadIdx.x, lane = tid & 63, w = tid >> 6;
  const int wr = w >> 2, wc = w & 3;
  const int rowBase = rb * 256;

  __shared__ __align__(16) u16 lds[65536];  // 128 KiB: A 2x32K | B 2x32K
  char* const lb = (char*)lds;

  const int tr = tid >> 3;
  const int swk = ((tid & 7) << 4) ^ ((((tr & 7) ^ (((tr >> 3) & 3) << 1)) << 4));
  const u16* aS[4]; const u16* bS[4];
  const u16* wBase = W13T + (size_t)e * (2 * IDIM) * HDIM;
#pragma unroll
  for (int s = 0; s < 4; ++s) {
    int pr = pairs[rowBase + s * 64 + tr];
    int tok = pr < 0 ? 0 : (pr >> 1);
    aS[s] = Xb + (size_t)tok * HDIM + (swk >> 1);
    bS[s] = wBase + (size_t)((tr >> 5) * IDIM + bn0 + s * 32 + (tr & 31)) * HDIM + (swk >> 1);
  }

#define STGA(b, h, kt) { GLD16(aS[(h)*2]   + (kt)*64, lb + (b)*32768 + (h)*16384 + tid*16); \
                         GLD16(aS[(h)*2+1] + (kt)*64, lb + (b)*32768 + (h)*16384 + 8192 + tid*16); }
#define STGB(b, h, kt) { GLD16(bS[(h)*2]   + (kt)*64, lb + 65536 + (b)*32768 + (h)*16384 + tid*16); \
                         GLD16(bS[(h)*2+1] + (kt)*64, lb + 65536 + (b)*32768 + (h)*16384 + 8192 + tid*16); }

  const int cl = lane & 31, hi = lane >> 5;
  const int swr = (((cl & 7) ^ (((cl >> 3) & 3) << 1)) << 4);
  const int hi16 = hi * 16;
  const int ko0 = (0  + hi16) ^ swr;
  const int ko1 = (32 + hi16) ^ swr;
  const int ko2 = (64 + hi16) ^ swr;
  const int ko3 = (96 + hi16) ^ swr;
  const int aFB = wr * 16384 + cl * 128;           // + mfi*4096
  const int bFB = 65536 + wc * 8192 + cl * 128;    // + nf*4096

#define LDA(d, b, mfi, K) d = *(const bf16x8*)(lb + (b)*32768 + aFB + (mfi)*4096 + ko##K)
#define LDB(d, b, nf, K)  d = *(const bf16x8*)(lb + (b)*32768 + bFB + (nf)*4096 + ko##K)

#define MF32(mq, A, BV) \
  _Pragma("unroll") for (int mf2 = 0; mf2 < 2; ++mf2) \
  _Pragma("unroll") for (int nf = 0; nf < 2; ++nf) \
  _Pragma("unroll") for (int ki = 0; ki < 2; ++ki) \
    acc[(mq)*2+mf2][nf] = __builtin_amdgcn_mfma_f32_32x32x16_bf16(A[mf2*2+ki], BV[nf*2+ki], acc[(mq)*2+mf2][nf], 0, 0, 0);

  f32x16 acc[4][2];
#pragma unroll
  for (int i = 0; i < 4; ++i)
#pragma unroll
    for (int j = 0; j < 2; ++j) acc[i][j] = (f32x16)0.f;

  // prologue: B(0)[4] A(0)[4] B(1)[4]; confirm B(0)+A(0)
  STGB(0, 0, 0); STGB(0, 1, 0); STGA(0, 0, 0); STGA(0, 1, 0); STGB(1, 0, 1); STGB(1, 1, 1);
  WAITVM(4);
  pbar();

  bf16x8 aF[4], bK0[4], bK1[4];
#define ITER1(b, t1, t2) { \
    /* ph1: mf0-1, ks0-1 */ \
    LDA(aF[0], b, 0, 0); LDA(aF[1], b, 0, 1); LDA(aF[2], b, 1, 0); LDA(aF[3], b, 1, 1); \
    LDB(bK0[0], b, 0, 0); LDB(bK0[1], b, 0, 1); LDB(bK0[2], b, 1, 0); LDB(bK0[3], b, 1, 1); \
    STGA((b)^1, 0, t1); \
    pbar(); \
    __builtin_amdgcn_s_setprio(1); MF32(0, aF, bK0); __builtin_amdgcn_s_setprio(0); \
    pbar(); \
    /* ph2: mf0-1, ks2-3 */ \
    LDA(aF[0], b, 0, 2); LDA(aF[1], b, 0, 3); LDA(aF[2], b, 1, 2); LDA(aF[3], b, 1, 3); \
    LDB(bK1[0], b, 0, 2); LDB(bK1[1], b, 0, 3); LDB(bK1[2], b, 1, 2); LDB(bK1[3], b, 1, 3); \
    STGA((b)^1, 1, t1); \
    pbar(); \
    __builtin_amdgcn_s_setprio(1); MF32(0, aF, bK1); __builtin_amdgcn_s_setprio(0); \
    pbar(); \
    /* ph3: mf2-3, ks0-1 */ \
    LDA(aF[0], b, 2, 0); LDA(aF[1], b, 2, 1); LDA(aF[2], b, 3, 0); LDA(aF[3], b, 3, 1); \
    STGB(b, 0, t2); \
    pbar(); \
    __builtin_amdgcn_s_setprio(1); MF32(1, aF, bK0); __builtin_amdgcn_s_setprio(0); \
    pbar(); \
    /* ph4: mf2-3, ks2-3 */ \
    LDA(aF[0], b, 2, 2); LDA(aF[1], b, 2, 3); LDA(aF[2], b, 3, 2); LDA(aF[3], b, 3, 3); \
    STGB(b, 1, t2); \
    pbar(); \
    __builtin_amdgcn_s_setprio(1); MF32(1, aF, bK1); __builtin_amdgcn_s_setprio(0); \
    WAITVM(4); \
    pbar(); \
  }

  for (int jj = 0; jj < 8; ++jj) {
    const int ta = (2 * jj + 1) & 15, tb = (2 * jj + 2) & 15, tc = (2 * jj + 3) & 15;
    ITER1(0, ta, tb);
    ITER1(1, tb, tc);
  }
#undef ITER1
#undef STGA
#undef STGB
#undef LDA
#undef LDB

  // epilogue: C/D (32x32): col=lane&31, row=(reg&3)+8*(reg>>2)+4*(lane>>5)  [m74/m101]
#pragma unroll
  for (int mf = 0; mf < 4; ++mf) {
#pragma unroll
    for (int reg = 0; reg < 16; ++reg) {
      int m = wr * 128 + mf * 32 + (reg & 3) + 8 * (reg >> 2) + 4 * hi;
      int pr = rowBase + m;
      int pair = pairs[pr];
      float rw = pair >= 0 ? rwf[pair] : 0.f;
      float gv = acc[mf][0][reg], uv = acc[mf][1][reg];
      float s = gv / (1.f + __expf(-gv));
      Hb[(size_t)pr * IDIM + bn0 + wc * 32 + cl] = f2bf(s * uv * rw);
    }
  }
}

// ======================= GEMM2: 256x256, splitK=2, 32x32x16, bf16 partials =======================
__global__ __launch_bounds__(512, 2) void gemm2_k(
    const u16* __restrict__ Hb, const u16* __restrict__ W2T,
    const int* __restrict__ meta, u16* __restrict__ part) {
  // nwg = 4*71*2 = 568 = 8*71
  int lin = blockIdx.x + 4 * blockIdx.y + 284 * blockIdx.z;
  int xcd = lin & 7, slot = lin >> 3;
  int flat = xcd * 71 + slot;
  int kz = flat / 284, rm = flat % 284;
  int bx = rm / 71, rb = rm % 71;
  if (rb >= meta[24]) return;
  const int e = meta[32 + rb];
  const int bn0 = bx * 256;
  const int kz0 = kz * 1408;                 // 22 K-tiles of 64
  const int tid = threadIdx.x, lane = tid & 63, w = tid >> 6;
  const int wr = w >> 2, wc = w & 3;
  const int rowBase = rb * 256;

  __shared__ __align__(16) u16 lds[65536];
  char* const lb = (char*)lds;

  const int tr = tid >> 3;
  const int swk = ((tid & 7) << 4) ^ ((((tr & 7) ^ (((tr >> 3) & 3) << 1)) << 4));
  const u16* aS[4]; const u16* bS[4];
  const u16* w2Base = W2T + (size_t)e * HDIM * IDIM;
#pragma unroll
  for (int s = 0; s < 4; ++s) {
    aS[s] = Hb + (size_t)(rowBase + s * 64 + tr) * IDIM + kz0 + (swk >> 1);
    bS[s] = w2Base + (size_t)(bn0 + s * 64 + tr) * IDIM + kz0 + (swk >> 1);
  }

#define STGA(b, h, kt) { GLD16(aS[(h)*2]   + (kt)*64, lb + (b)*32768 + (h)*16384 + tid*16); \
                         GLD16(aS[(h)*2+1] + (kt)*64, lb + (b)*32768 + (h)*16384 + 8192 + tid*16); }
#define STGB(b, h, kt) { GLD16(bS[(h)*2]   + (kt)*64, lb + 65536 + (b)*32768 + (h)*16384 + tid*16); \
                         GLD16(bS[(h)*2+1] + (kt)*64, lb + 65536 + (b)*32768 + (h)*16384 + 8192 + tid*16); }

  const int cl = lane & 31, hi = lane >> 5;
  const int swr = (((cl & 7) ^ (((cl >> 3) & 3) << 1)) << 4);
  const int hi16 = hi * 16;
  const int ko0 = (0  + hi16) ^ swr;
  const int ko1 = (32 + hi16) ^ swr;
  const int ko2 = (64 + hi16) ^ swr;
  const int ko3 = (96 + hi16) ^ swr;
  const int aFB = wr * 16384 + cl * 128;
  const int bFB = 65536 + wc * 8192 + cl * 128;

#define LDA(d, b, mfi, K) d = *(const bf16x8*)(lb + (b)*32768 + aFB + (mfi)*4096 + ko##K)
#define LDB(d, b, nf, K)  d = *(const bf16x8*)(lb + (b)*32768 + bFB + (nf)*4096 + ko##K)

  f32x16 acc[4][2];
#pragma unroll
  for (int i = 0; i < 4; ++i)
#pragma unroll
    for (int j = 0; j < 2; ++j) acc[i][j] = (f32x16)0.f;

  STGB(0, 0, 0); STGB(0, 1, 0); STGA(0, 0, 0); STGA(0, 1, 0); STGB(1, 0, 1); STGB(1, 1, 1);
  WAITVM(4);
  pbar();

  bf16x8 aF[4], bK0[4], bK1[4];
#define ITER2(b, t1, t2) { \
    LDA(aF[0], b, 0, 0); LDA(aF[1], b, 0, 1); LDA(aF[2], b, 1, 0); LDA(aF[3], b, 1, 1); \
    LDB(bK0[0], b, 0, 0); LDB(bK0[1], b, 0, 1); LDB(bK0[2], b, 1, 0); LDB(bK0[3], b, 1, 1); \
    STGA((b)^1, 0, t1); \
    pbar(); \
    __builtin_amdgcn_s_setprio(1); MF32(0, aF, bK0); __builtin_amdgcn_s_setprio(0); \
    pbar(); \
    LDA(aF[0], b, 0, 2); LDA(aF[1], b, 0, 3); LDA(aF[2], b, 1, 2); LDA(aF[3], b, 1, 3); \
    LDB(bK1[0], b, 0, 2); LDB(bK1[1], b, 0, 3); LDB(bK1[2], b, 1, 2); LDB(bK1[3], b, 1, 3); \
    STGA((b)^1, 1, t1); \
    pbar(); \
    __builtin_amdgcn_s_setprio(1); MF32(0, aF, bK1); __builtin_amdgcn_s_setprio(0); \
    pbar(); \
    LDA(aF[0], b, 2, 0); LDA(aF[1], b, 2, 1); LDA(aF[2], b, 3, 0); LDA(aF[3], b, 3, 1); \
    STGB(b, 0, t2); \
    pbar(); \
    __builtin_amdgcn_s_setprio(1); MF32(1, aF, bK0); __builtin_amdgcn_s_setprio(0); \
    pbar(); \
    LDA(aF[0], b, 2, 2); LDA(aF[1], b, 2, 3); LDA(aF[2], b, 3, 2); LDA(aF[3], b, 3, 3); \
    STGB(b, 1, t2); \
    pbar(); \
    __builtin_amdgcn_s_setprio(1); MF32(1, aF, bK1); __builtin_amdgcn_s_setprio(0); \
    WAITVM(4); \
    pbar(); \
  }

  for (int jj = 0; jj < 11; ++jj) {
    const int t1 = 2 * jj + 1;
    const int tb = (2 * jj + 2 < 22) ? 2 * jj + 2 : 0;
    const int tc = (2 * jj + 3 < 22) ? 2 * jj + 3 : 0;
    ITER2(0, t1, tb);
    ITER2(1, tb, tc);
  }
#undef ITER2
#undef STGA
#undef STGB
#undef LDA
#undef LDB

  u16* pz = part + (size_t)kz * PARTSZ;
#pragma unroll
  for (int mf = 0; mf < 4; ++mf) {
#pragma unroll
    for (int reg = 0; reg < 16; ++reg) {
      int m = rowBase + wr * 128 + mf * 32 + (reg & 3) + 8 * (reg >> 2) + 4 * hi;
      u16* prow = pz + (size_t)m * HDIM + bn0 + wc * 64 + cl;
      prow[0]  = f2bf(acc[mf][0][reg]);
      prow[32] = f2bf(acc[mf][1][reg]);
    }
  }
}

// out[t] = sum over 2 pair-rows x 2 splitK slots of bf16 partials
__global__ void reduce_k(const u16* __restrict__ part, const int* __restrict__ inv,
                         float* __restrict__ out) {
  int t = blockIdx.x;
  int c = threadIdx.x * 8;
  int r0 = inv[2 * t], r1 = inv[2 * t + 1];
  u16x8 a0 = *(const u16x8*)&part[(size_t)r0 * HDIM + c];
  u16x8 a1 = *(const u16x8*)&part[(size_t)r1 * HDIM + c];
  u16x8 b0 = *(const u16x8*)&part[PARTSZ + (size_t)r0 * HDIM + c];
  u16x8 b1 = *(const u16x8*)&part[PARTSZ + (size_t)r1 * HDIM + c];
  float4 o0, o1;
  o0.x = bf2f(a0[0]) + bf2f(a1[0]) + bf2f(b0[0]) + bf2f(b1[0]);
  o0.y = bf2f(a0[1]) + bf2f(a1[1]) + bf2f(b0[1]) + bf2f(b1[1]);
  o0.z = bf2f(a0[2]) + bf2f(a1[2]) + bf2f(b0[2]) + bf2f(b1[2]);
  o0.w = bf2f(a0[3]) + bf2f(a1[3]) + bf2f(b0[3]) + bf2f(b1[3]);
  o1.x = bf2f(a0[4]) + bf2f(a1[4]) + bf2f(b0[4]) + bf2f(b1[4]);
  o1.y = bf2f(a0[5]) + bf2f(a1[5]) + bf2f(b0[5]) + bf2f(b1[5]);
  o1.z = bf2f(a0[6]) + bf2f(a1[6]) + bf2f(b0[6]) + bf2f(b1[6]);
  o1.w = bf2f(a0[7]) + bf2f(a1[7]) + bf2f(b0[7]) + bf2f(b1[7]);
  *(float4*)&out[(size_t)t * HDIM + c] = o0;
  *(float4*)&out[(size_t)t * HDIM + c + 4] = o1;
}

extern "C" void kernel_launch(void* const* d_in, const int* in_sizes, int n_in,
                              void* d_out, int out_size, void* d_ws, size_t ws_size,
                              hipStream_t stream) {
  const float* X = (const float*)d_in[0];
  const int* routing = (const int*)d_in[1];
  const float* rwf = (const float*)d_in[2];
  const float* w13 = (const float*)d_in[3];
  const float* w2 = (const float*)d_in[4];
  float* out = (float*)d_out;
  char* ws = (char*)d_ws;

  if (ws_size < WS_NEED) {
    hipMemsetAsync(d_out, 0, (size_t)T_TOK * HDIM * sizeof(float), stream);
    return;
  }

  int* meta = (int*)ws;
  int* pairs = (int*)(ws + 1024);
  int* inv = (int*)(ws + 73728);
  u16* Xb = (u16*)(ws + XB_OFF);
  u16* W13T = (u16*)(ws + W13T_OFF);
  u16* W2T = (u16*)(ws + W2T_OFF);
  u16* Hb = (u16*)(ws + H_OFF);
  u16* part = (u16*)(ws + W13T_OFF);   // aliases W13T (dead after gemm1); 2x bf16 slots = 74.5 MB

  fillinit_k<<<MAXRB, 256, 0, stream>>>(pairs, meta);
  count_k<<<NPAIR / 256, 256, 0, stream>>>(routing, meta);
  scan_k<<<1, 64, 0, stream>>>(meta);
  scatter_k<<<NPAIR / 256, 256, 0, stream>>>(routing, meta, pairs, inv);
  conv_x<<<(T_TOK * HDIM / 8) / 256, 256, 0, stream>>>(X, Xb);
  transpose_cvt<<<dim3(5632 / 64, 1024 / 64, NEXP), 256, 0, stream>>>(w13, W13T, 1024, 5632);
  transpose_cvt<<<dim3(1024 / 64, 2816 / 64, NEXP), 256, 0, stream>>>(w2, W2T, 2816, 1024);
  gemm1_k<<<dim3(22, MAXRB), 512, 0, stream>>>(Xb, W13T, pairs, meta, rwf, Hb);
  gemm2_k<<<dim3(4, MAXRB, 2), 512, 0, stream>>>(Hb, W2T, meta, part);
  reduce_k<<<T_TOK, 128, 0, stream>>>(part, inv, out);
}

// Round 8
// 575.832 us; speedup vs baseline: 1.1002x; 1.1002x over previous
//
#include <hip/hip_runtime.h>

typedef unsigned short u16;
typedef unsigned int u32;
typedef __bf16 bf16x8 __attribute__((ext_vector_type(8)));
typedef float f32x4 __attribute__((ext_vector_type(4)));
typedef u16 u16x8 __attribute__((ext_vector_type(8)));

#define T_TOK 8192
#define HDIM 1024
#define IDIM 2816
#define NEXP 8
#define NPAIR (T_TOK * 2)
#define MAXRB 71   // max padded 256-row blocks: 16384/256 + 7

// workspace layout (bytes)
// meta @0 (1K) | pairs @1024 | inv @73728 |
#define XB_OFF   (147456u)
#define W13T_OFF (XB_OFF + 16777216u)            // w13^T bf16 [E][5632][1024]; part (fp32) aliases after gemm1
#define W2T_OFF  (W13T_OFF + 92274688u)          // w2^T bf16 [E][1024][2816]
#define H_OFF    (W2T_OFF + 46137344u)           // h bf16 [18176][2816]
#define WS_NEED  ((size_t)H_OFF + 102367232u)    // ~257.7 MB

__device__ __forceinline__ u16 f2bf(float f) {
  u32 u = __builtin_bit_cast(u32, f);
  u32 r = u + 0x7fffu + ((u >> 16) & 1u);
  return (u16)(r >> 16);
}

#define GLD16(g, l) __builtin_amdgcn_global_load_lds( \
    (const __attribute__((address_space(1))) void*)(g), \
    (__attribute__((address_space(3))) void*)(l), 16, 0, 0)

#define WAITVM(N) asm volatile("s_waitcnt vmcnt(" #N ")" ::: "memory")

__device__ __forceinline__ void pbar() {
  __builtin_amdgcn_sched_barrier(0);
  asm volatile("" ::: "memory");
  __builtin_amdgcn_s_barrier();
  asm volatile("" ::: "memory");
  __builtin_amdgcn_sched_barrier(0);
}

// ---------------- routing ----------------
__global__ void fillinit_k(int* __restrict__ pairs, int* __restrict__ meta) {
  if (blockIdx.x == 0 && threadIdx.x < 16) meta[threadIdx.x] = 0;
  pairs[blockIdx.x * 256 + threadIdx.x] = -1;
}

__global__ void count_k(const int* __restrict__ routing, int* __restrict__ meta) {
  int i = blockIdx.x * 256 + threadIdx.x;
  if (i < NPAIR) atomicAdd(&meta[routing[i]], 1);
}

// meta: [0..7] counts, [8..15] cursors, [16..23] startRow, [24] totalRB, [32..102] rbExpert
__global__ void scan_k(int* __restrict__ meta) {
  if (threadIdx.x == 0) {
    int rb = 0;
    for (int e = 0; e < NEXP; ++e) {
      meta[16 + e] = rb * 256;
      int nrb = (meta[e] + 255) >> 8;
      for (int i = 0; i < nrb; ++i) meta[32 + rb + i] = e;
      rb += nrb;
    }
    meta[24] = rb;
  }
}

__global__ void scatter_k(const int* __restrict__ routing, int* __restrict__ meta,
                          int* __restrict__ pairs, int* __restrict__ inv) {
  int i = blockIdx.x * 256 + threadIdx.x;
  if (i < NPAIR) {
    int e = routing[i];
    int pos = atomicAdd(&meta[8 + e], 1);
    int row = meta[16 + e] + pos;
    pairs[row] = i;
    inv[i] = row;
  }
}

// ---------------- converts ----------------
__global__ void conv_x(const float* __restrict__ in, u16* __restrict__ out) {
  int i = blockIdx.x * 256 + threadIdx.x;   // covers T*H/8
  float4 a = ((const float4*)in)[2 * i];
  float4 b = ((const float4*)in)[2 * i + 1];
  u16x8 o = { f2bf(a.x), f2bf(a.y), f2bf(a.z), f2bf(a.w),
              f2bf(b.x), f2bf(b.y), f2bf(b.z), f2bf(b.w) };
  ((u16x8*)out)[i] = o;
}

// out[c][r] = bf16(in[r][c]); 64x64 tiles; XOR-swizzled LDS (4-way -> 2-way free)
#define TSW(r, c) (((((c) >> 2) ^ ((((r) >> 4) & 3) << 2)) << 2) | ((c) & 3))
__global__ void transpose_cvt(const float* __restrict__ in, u16* __restrict__ out,
                              int R, int C) {
  __shared__ float tile[64][68];
  size_t base = (size_t)blockIdx.z * (size_t)R * (size_t)C;
  in += base; out += base;
  int t = threadIdx.x;
  int r0 = blockIdx.y * 64, c0 = blockIdx.x * 64;
  int lr = t >> 4, cb = t & 15;
#pragma unroll
  for (int p = 0; p < 4; ++p) {
    int row = p * 16 + lr;
    float4 v = *(const float4*)&in[(size_t)(r0 + row) * C + c0 + cb * 4];
    int pc = ((cb ^ ((p & 3) << 2)) << 2);
    tile[row][pc] = v.x; tile[row][pc + 1] = v.y;
    tile[row][pc + 2] = v.z; tile[row][pc + 3] = v.w;
  }
  __syncthreads();
  int oc = t >> 2, g0 = (t & 3) * 2;
#pragma unroll
  for (int gg = 0; gg < 2; ++gg) {
    int g = g0 + gg;
    u16x8 o = { f2bf(tile[g * 8 + 0][TSW(g * 8 + 0, oc)]), f2bf(tile[g * 8 + 1][TSW(g * 8 + 1, oc)]),
                f2bf(tile[g * 8 + 2][TSW(g * 8 + 2, oc)]), f2bf(tile[g * 8 + 3][TSW(g * 8 + 3, oc)]),
                f2bf(tile[g * 8 + 4][TSW(g * 8 + 4, oc)]), f2bf(tile[g * 8 + 5][TSW(g * 8 + 5, oc)]),
                f2bf(tile[g * 8 + 6][TSW(g * 8 + 6, oc)]), f2bf(tile[g * 8 + 7][TSW(g * 8 + 7, oc)]) };
    *(u16x8*)&out[(size_t)(c0 + oc) * R + r0 + g * 8] = o;
  }
}

// ======================= GEMM1: 256x256, 16x16x32, frag-pipelined (reads 1 phase ahead) =========
// B-tile rows permuted: row r -> (r>>5)&1 ? up : gate, col bn0 + (r>>6)*32 + (r&31).
// Waves 2M x 4N; per-wave 128 rows x 64 B-rows. Each window reads the NEXT phase's frags so
// MFMA waits counted lgkmcnt (not 0) and LDS streams under the matrix pipe.
__global__ __launch_bounds__(512, 2) void gemm1_k(
    const u16* __restrict__ Xb, const u16* __restrict__ W13T,
    const int* __restrict__ pairs, const int* __restrict__ meta,
    const float* __restrict__ rwf, u16* __restrict__ Hb) {
  int lin = blockIdx.x + 22 * blockIdx.y;
  int xcd = lin & 7, slot = lin >> 3;
  int flat = (xcd < 2) ? xcd * 196 + slot : 392 + (xcd - 2) * 195 + slot;
  int bx = flat / 71, rb = flat % 71;
  if (rb >= meta[24]) return;
  const int e = meta[32 + rb];
  const int bn0 = bx * 128;
  const int tid = threadIdx.x, lane = tid & 63, w = tid >> 6;
  const int wr = w >> 2, wc = w & 3;
  const int rowBase = rb * 256;

  __shared__ __align__(16) u16 lds[65536];  // 128 KiB: A 2x32K | B 2x32K
  char* const lb = (char*)lds;

  const int tr = tid >> 3;                               // 0..63
  const int swk = ((tid & 7) << 4) ^ ((tr & 7) << 4);    // inverse-swizzled source byte
  const u16* aS[4]; const u16* bS[4];
  const u16* wBase = W13T + (size_t)e * (2 * IDIM) * HDIM;
#pragma unroll
  for (int s = 0; s < 4; ++s) {
    int pr = pairs[rowBase + s * 64 + tr];
    int tok = pr < 0 ? 0 : (pr >> 1);
    aS[s] = Xb + (size_t)tok * HDIM + (swk >> 1);
    bS[s] = wBase + (size_t)((tr >> 5) * IDIM + bn0 + s * 32 + (tr & 31)) * HDIM + (swk >> 1);
  }

#define STGA(b, h, kt) { GLD16(aS[(h)*2]   + (kt)*64, lb + (b)*32768 + (h)*16384 + tid*16); \
                         GLD16(aS[(h)*2+1] + (kt)*64, lb + (b)*32768 + (h)*16384 + 8192 + tid*16); }
#define STGB(b, h, kt) { GLD16(bS[(h)*2]   + (kt)*64, lb + 65536 + (b)*32768 + (h)*16384 + tid*16); \
                         GLD16(bS[(h)*2+1] + (kt)*64, lb + 65536 + (b)*32768 + (h)*16384 + 8192 + tid*16); }

  const int l15 = lane & 15, l4 = lane >> 4, l7 = lane & 7;
  const int ko0 = (l4 * 16) ^ (l7 << 4);
  const int ko1 = (64 + l4 * 16) ^ (l7 << 4);
  const int aFB = wr * 16384 + l15 * 128;                // + mh*8192 + mf*2048
  const int bFB = 65536 + (wc * 64 + l15) * 128;         // + nf*2048

#define LDA(d, b, mh, mf, ko) d = *(const bf16x8*)(lb + (b)*32768 + aFB + (mh)*8192 + (mf)*2048 + (ko))
#define LDB(d, b, nf, ko)     d = *(const bf16x8*)(lb + (b)*32768 + bFB + (nf)*2048 + (ko))

#define MFQ(mh, A, B) \
  _Pragma("unroll") for (int mf = 0; mf < 4; ++mf) \
  _Pragma("unroll") for (int nf = 0; nf < 4; ++nf) \
    acc[(mh)*4+mf][nf] = __builtin_amdgcn_mfma_f32_16x16x32_bf16(A[mf], B[nf], acc[(mh)*4+mf][nf], 0, 0, 0);

  f32x4 acc[8][4];
  const f32x4 fz = {0.f, 0.f, 0.f, 0.f};
#pragma unroll
  for (int i = 0; i < 8; ++i)
#pragma unroll
    for (int j = 0; j < 4; ++j) acc[i][j] = fz;

  // prologue: B(0)[4] A(0)[4] B(1)[4] -> 12 glds; confirm B(0)+A(0) (4 B(1) glds remain)
  STGB(0, 0, 0); STGB(0, 1, 0); STGA(0, 0, 0); STGA(0, 1, 0); STGB(1, 0, 1); STGB(1, 1, 1);
  WAITVM(4);
  pbar();

  bf16x8 aA[4], aB[4], bK0[4], bK1[4];
  // pre-read M_P1(0) frags: aA = A(0)[mh0,ks0], bK0 = B(0)[ks0]
#pragma unroll
  for (int f = 0; f < 4; ++f) { LDA(aA[f], 0, 0, f, ko0); LDB(bK0[f], 0, f, ko0); }

  // Per tile t (buf b): W_Pk reads frags for M_P(k+1); vmcnt(2) once/tile at W_P4
  // (confirms A(t+1)+B(t+1); leaves STGB(t+2) half0 in flight).
#define TILE1(b, t1, t2) { \
    /* W_P1: R aB=A[b,mh0,ks1], bK1=B[b,ks1]; S STGA(b^1,0,t1) */ \
    _Pragma("unroll") for (int f = 0; f < 4; ++f) { LDA(aB[f], b, 0, f, ko1); LDB(bK1[f], b, f, ko1); } \
    STGA((b)^1, 0, t1); \
    pbar(); \
    __builtin_amdgcn_s_setprio(1); MFQ(0, aA, bK0); __builtin_amdgcn_s_setprio(0); \
    pbar(); \
    /* W_P2: R aA=A[b,mh1,ks0]; S STGA(b^1,1,t1) */ \
    _Pragma("unroll") for (int f = 0; f < 4; ++f) { LDA(aA[f], b, 1, f, ko0); } \
    STGA((b)^1, 1, t1); \
    pbar(); \
    __builtin_amdgcn_s_setprio(1); MFQ(0, aB, bK1); __builtin_amdgcn_s_setprio(0); \
    pbar(); \
    /* W_P3: R aB=A[b,mh1,ks1]; S STGB(b,0,t2) */ \
    _Pragma("unroll") for (int f = 0; f < 4; ++f) { LDA(aB[f], b, 1, f, ko1); } \
    STGB(b, 0, t2); \
    pbar(); \
    __builtin_amdgcn_s_setprio(1); MFQ(1, aA, bK0); __builtin_amdgcn_s_setprio(0); \
    pbar(); \
    /* W_P4: vmcnt(2); R aA=A[b^1,mh0,ks0], bK0=B[b^1,ks0]; S STGB(b,1,t2) */ \
    WAITVM(2); \
    _Pragma("unroll") for (int f = 0; f < 4; ++f) { LDA(aA[f], (b)^1, 0, f, ko0); LDB(bK0[f], (b)^1, f, ko0); } \
    STGB(b, 1, t2); \
    pbar(); \
    __builtin_amdgcn_s_setprio(1); MFQ(1, aB, bK1); __builtin_amdgcn_s_setprio(0); \
    pbar(); \
  }

  for (int jj = 0; jj < 8; ++jj) {
    const int ta = (2 * jj + 1) & 15, tb = (2 * jj + 2) & 15, tc = (2 * jj + 3) & 15;
    TILE1(0, ta, tb);
    TILE1(1, tb, tc);
  }
#undef TILE1
#undef STGA
#undef STGB
#undef LDA
#undef LDB
#undef MFQ

  // epilogue: C/D col=lane&15, row=(lane>>4)*4+j; gate = acc[mf][0,1], up = acc[mf][2,3]
  const int ct = l4;
#pragma unroll
  for (int mf = 0; mf < 8; ++mf) {
#pragma unroll
    for (int j = 0; j < 4; ++j) {
      int m = wr * 128 + mf * 16 + ct * 4 + j;
      int pr = rowBase + m;
      int pair = pairs[pr];
      float rw = pair >= 0 ? rwf[pair] : 0.f;
      u16* hrow = Hb + (size_t)pr * IDIM + bn0 + wc * 32 + l15;
#pragma unroll
      for (int g = 0; g < 2; ++g) {
        float gv = acc[mf][g][j], uv = acc[mf][g + 2][j];
        float s = gv / (1.f + __expf(-gv));
        hrow[g * 16] = f2bf(s * uv * rw);
      }
    }
  }
}

// ======================= GEMM2 (4-phase, BM=BN=128, 2 blocks/CU, no atomics) — R5 control ======
__global__ __launch_bounds__(256, 2) void gemm2_k(
    const u16* __restrict__ Hb, const u16* __restrict__ W2T,
    const int* __restrict__ meta, float* __restrict__ part) {
  int lin = blockIdx.y + 142 * blockIdx.x;
  int xcd = lin & 7, slot = lin >> 3;
  int flat = xcd * 142 + slot;
  int bx = flat / 142, rb2 = flat % 142;
  if (rb2 >= meta[24] * 2) return;
  const int e = meta[32 + (rb2 >> 1)];
  const int bn0 = bx * 128;
  const int tid = threadIdx.x, lane = tid & 63, w = tid >> 6;
  const int wr = w >> 1, wc = w & 1;
  const int rowBase = rb2 * 128;

  __shared__ __align__(16) u16 lds2[32768];
  char* const lb = (char*)lds2;

  const int sr = tid >> 3;
  const int swk = ((tid & 7) << 4) ^ ((sr & 7) << 4);
  const u16* aS[4]; const u16* bS[4];
#pragma unroll
  for (int j = 0; j < 4; ++j) {
    aS[j] = Hb + (size_t)(rowBase + j * 32 + sr) * IDIM + (swk >> 1);
    bS[j] = W2T + (size_t)e * HDIM * IDIM + (size_t)(bn0 + j * 32 + sr) * IDIM + (swk >> 1);
  }

#define STG_A2(b, kt) { GLD16(aS[0] + (kt)*64, lb + (b)*16384 + tid*16); \
                        GLD16(aS[1] + (kt)*64, lb + (b)*16384 + 4096 + tid*16); \
                        GLD16(aS[2] + (kt)*64, lb + (b)*16384 + 8192 + tid*16); \
                        GLD16(aS[3] + (kt)*64, lb + (b)*16384 + 12288 + tid*16); }
#define STG_B2(b, kt) { GLD16(bS[0] + (kt)*64, lb + 32768 + (b)*16384 + tid*16); \
                        GLD16(bS[1] + (kt)*64, lb + 32768 + (b)*16384 + 4096 + tid*16); \
                        GLD16(bS[2] + (kt)*64, lb + 32768 + (b)*16384 + 8192 + tid*16); \
                        GLD16(bS[3] + (kt)*64, lb + 32768 + (b)*16384 + 12288 + tid*16); }

  const int l15 = lane & 15, l4 = lane >> 4, l7 = lane & 7;
  const int ko0 = (l4 * 16) ^ (l7 << 4);
  const int ko1 = (64 + l4 * 16) ^ (l7 << 4);
  const int aFB = (wr * 64 + l15) * 128;
  const int bFB = (wc * 64 + l15) * 128;

#define LDAF2(d, b, mf, ko) d = *(const bf16x8*)(lb + (b)*16384 + aFB + (mf)*2048 + (ko))
#define LDBF2(d, b, nf, ko) d = *(const bf16x8*)(lb + 32768 + (b)*16384 + bFB + (nf)*2048 + (ko))

#define MF16v(A, B) \
  _Pragma("unroll") for (int mf = 0; mf < 4; ++mf) \
  _Pragma("unroll") for (int nf = 0; nf < 4; ++nf) \
    acc[mf][nf] = __builtin_amdgcn_mfma_f32_16x16x32_bf16(A[mf], B[nf], acc[mf][nf], 0, 0, 0);

  f32x4 acc[4][4];
  const f32x4 fz = {0.f, 0.f, 0.f, 0.f};
#pragma unroll
  for (int i = 0; i < 4; ++i)
#pragma unroll
    for (int j = 0; j < 4; ++j) acc[i][j] = fz;

  STG_A2(0, 0); STG_B2(0, 0); STG_A2(1, 1);
  WAITVM(4);
  pbar();

  bf16x8 a0[4], a1[4], b0[4], b1[4];
  for (int i = 0; i < 22; ++i) {
    const int t1 = 2 * i + 1;
    const int nt0 = (2 * i + 2 < 44) ? 2 * i + 2 : 0;
    const int nt1 = (2 * i + 3 < 44) ? 2 * i + 3 : 0;
#pragma unroll
    for (int f = 0; f < 4; ++f) { LDAF2(a0[f], 0, f, ko0); LDAF2(a1[f], 0, f, ko1);
                                  LDBF2(b0[f], 0, f, ko0); LDBF2(b1[f], 0, f, ko1); }
    STG_B2(1, t1);
    pbar();
    __builtin_amdgcn_s_setprio(1); MF16v(a0, b0); __builtin_amdgcn_s_setprio(0);
    pbar();
    STG_A2(0, nt0);
    pbar();
    __builtin_amdgcn_s_setprio(1); MF16v(a1, b1); __builtin_amdgcn_s_setprio(0);
    WAITVM(4);
    pbar();
#pragma unroll
    for (int f = 0; f < 4; ++f) { LDAF2(a0[f], 1, f, ko0); LDAF2(a1[f], 1, f, ko1);
                                  LDBF2(b0[f], 1, f, ko0); LDBF2(b1[f], 1, f, ko1); }
    STG_B2(0, nt0);
    pbar();
    __builtin_amdgcn_s_setprio(1); MF16v(a0, b0); __builtin_amdgcn_s_setprio(0);
    pbar();
    STG_A2(1, nt1);
    pbar();
    __builtin_amdgcn_s_setprio(1); MF16v(a1, b1); __builtin_amdgcn_s_setprio(0);
    WAITVM(4);
    pbar();
  }
#undef STG_A2
#undef STG_B2
#undef LDAF2
#undef LDBF2
#undef MF16v

  WAITVM(0);
  const int ct = l4;
#pragma unroll
  for (int mf = 0; mf < 4; ++mf) {
#pragma unroll
    for (int j = 0; j < 4; ++j) {
      int m = rowBase + wr * 64 + mf * 16 + ct * 4 + j;
      float* prow = part + (size_t)m * HDIM + bn0 + wc * 64 + l15;
#pragma unroll
      for (int nf = 0; nf < 4; ++nf) prow[nf * 16] = acc[mf][nf][j];
    }
  }
}

// out[t] = part[inv[2t]] + part[inv[2t+1]]
__global__ void reduce_k(const float* __restrict__ part, const int* __restrict__ inv,
                         float* __restrict__ out) {
  int t = blockIdx.x;
  int c = threadIdx.x * 4;
  int r0 = inv[2 * t], r1 = inv[2 * t + 1];
  float4 a = *(const float4*)&part[(size_t)r0 * HDIM + c];
  float4 b = *(const float4*)&part[(size_t)r1 * HDIM + c];
  float4 o = { a.x + b.x, a.y + b.y, a.z + b.z, a.w + b.w };
  *(float4*)&out[(size_t)t * HDIM + c] = o;
}

extern "C" void kernel_launch(void* const* d_in, const int* in_sizes, int n_in,
                              void* d_out, int out_size, void* d_ws, size_t ws_size,
                              hipStream_t stream) {
  const float* X = (const float*)d_in[0];
  const int* routing = (const int*)d_in[1];
  const float* rwf = (const float*)d_in[2];
  const float* w13 = (const float*)d_in[3];
  const float* w2 = (const float*)d_in[4];
  float* out = (float*)d_out;
  char* ws = (char*)d_ws;

  if (ws_size < WS_NEED) {
    hipMemsetAsync(d_out, 0, (size_t)T_TOK * HDIM * sizeof(float), stream);
    return;  // out stays 0 -> visible failure
  }

  int* meta = (int*)ws;
  int* pairs = (int*)(ws + 1024);
  int* inv = (int*)(ws + 73728);
  u16* Xb = (u16*)(ws + XB_OFF);
  u16* W13T = (u16*)(ws + W13T_OFF);
  u16* W2T = (u16*)(ws + W2T_OFF);
  u16* Hb = (u16*)(ws + H_OFF);
  float* part = (float*)(ws + W13T_OFF);   // aliases W13T (dead after gemm1); 74.5 MB

  fillinit_k<<<MAXRB, 256, 0, stream>>>(pairs, meta);
  count_k<<<NPAIR / 256, 256, 0, stream>>>(routing, meta);
  scan_k<<<1, 64, 0, stream>>>(meta);
  scatter_k<<<NPAIR / 256, 256, 0, stream>>>(routing, meta, pairs, inv);
  conv_x<<<(T_TOK * HDIM / 8) / 256, 256, 0, stream>>>(X, Xb);
  transpose_cvt<<<dim3(5632 / 64, 1024 / 64, NEXP), 256, 0, stream>>>(w13, W13T, 1024, 5632);
  transpose_cvt<<<dim3(1024 / 64, 2816 / 64, NEXP), 256, 0, stream>>>(w2, W2T, 2816, 1024);
  gemm1_k<<<dim3(22, MAXRB), 512, 0, stream>>>(Xb, W13T, pairs, meta, rwf, Hb);
  gemm2_k<<<dim3(8, 2 * MAXRB), 256, 0, stream>>>(Hb, W2T, meta, part);
  reduce_k<<<T_TOK, 256, 0, stream>>>(part, inv, out);
}